// Round 14
// baseline (217.965 us; speedup 1.0000x reference)
//
#include <hip/hip_runtime.h>
#include <cstddef>

#define NB 64
#define NP 1024
#define NPTS (NB * NP)

typedef __attribute__((ext_vector_type(8))) short v8s;
typedef __attribute__((ext_vector_type(4))) float f32x4;

__device__ __forceinline__ float dist2(const float4 pi, const float sqi, const float4 pq) {
    const float dot = fmaf(pi.z, pq.z, fmaf(pi.y, pq.y, pi.x * pq.x));
    return fmaf(-2.0f, dot, sqi + pq.w);
}

__device__ __forceinline__ void pack8(const float* w, v8s& hv, v8s& lv) {
    union { v8s v; unsigned int u[4]; } H, L;
#pragma unroll
    for (int p = 0; p < 4; ++p) {
        unsigned int a = __float_as_uint(w[2 * p]);
        unsigned int b = __float_as_uint(w[2 * p + 1]);
        unsigned int ha = a & 0xffff0000u, hb = b & 0xffff0000u;
        H.u[p] = (ha >> 16) | hb;
        float la = w[2 * p] - __uint_as_float(ha);
        float lb = w[2 * p + 1] - __uint_as_float(hb);
        L.u[p] = (__float_as_uint(la) >> 16) | (__float_as_uint(lb) & 0xffff0000u);
    }
    hv = H.v; lv = L.v;
}

// ---------------------------------------------------------------------------
// Direct A-fragment path (round-11..13 verified):
//  - j from wave-preloaded idxa/idxb via ds_bpermute (no per-tile VMEM)
//  - raw row slices fetched into 8 float4 regs (4-deep pipelined by caller)
//  - pack applies the EXACT add/relu/hi-lo split -> bit-identical values
// ---------------------------------------------------------------------------
template <int PT, int KP, int KREAL>
__device__ __forceinline__ void frag_fetch(
    const float* __restrict__ U, const float* __restrict__ V,
    int idxa, int idxb, int pb0, int tt, int lane, float4 r[8])
{
    constexpr int KSH = (KP == 8) ? 3 : 2;
    const int er = lane & 15;            // this lane's edge row
    const int quad = lane >> 4;          // 8-channel slice
    const int p = er >> KSH;
    int k = er & (KP - 1);
    if (k >= KREAL) k = 0;               // duplicate-k rows reuse the k=0 row
    const int li = (tt * PT + p) * 6 + k;
    const int ja = __builtin_amdgcn_ds_bpermute(li << 2, idxa);
    const int jb = __builtin_amdgcn_ds_bpermute(((li - 64) & 63) << 2, idxb);
    const int j = (li < 64) ? ja : jb;
    const int pt = pb0 + tt * PT + p;
    const float* vrow = V + (size_t)j * 64 + quad * 8;
    const float* urow = U + (size_t)pt * 64 + quad * 8;
    r[0] = *(const float4*)(vrow + 0);
    r[1] = *(const float4*)(vrow + 4);
    r[2] = *(const float4*)(vrow + 32);
    r[3] = *(const float4*)(vrow + 36);
    r[4] = *(const float4*)(urow + 0);
    r[5] = *(const float4*)(urow + 4);
    r[6] = *(const float4*)(urow + 32);
    r[7] = *(const float4*)(urow + 36);
}

__device__ __forceinline__ void frag_pack(const float4 r[8], v8s ah[2], v8s al[2])
{
#pragma unroll
    for (int ks = 0; ks < 2; ++ks) {
        const float4 v0 = r[ks * 2 + 0], v1 = r[ks * 2 + 1];
        const float4 u0 = r[4 + ks * 2 + 0], u1 = r[4 + ks * 2 + 1];
        float w[8];
        w[0] = fmaxf(u0.x + v0.x, 0.0f);
        w[1] = fmaxf(u0.y + v0.y, 0.0f);
        w[2] = fmaxf(u0.z + v0.z, 0.0f);
        w[3] = fmaxf(u0.w + v0.w, 0.0f);
        w[4] = fmaxf(u1.x + v1.x, 0.0f);
        w[5] = fmaxf(u1.y + v1.y, 0.0f);
        w[6] = fmaxf(u1.z + v1.z, 0.0f);
        w[7] = fmaxf(u1.w + v1.w, 0.0f);
        pack8(w, ah[ks], al[ks]);
    }
}

// 24-MFMA edge tile (same acc order as all prior passing versions).
__device__ __forceinline__ void edge_mfma(const v8s ah[2], const v8s al[2],
                                          const v8s bh[4][2], const v8s bl[4][2],
                                          f32x4 acc[4])
{
#pragma unroll
    for (int nt = 0; nt < 4; ++nt) acc[nt] = (f32x4){0.f, 0.f, 0.f, 0.f};
#pragma unroll
    for (int nt = 0; nt < 4; ++nt) {
#pragma unroll
        for (int ks = 0; ks < 2; ++ks) {
            acc[nt] = __builtin_amdgcn_mfma_f32_16x16x32_bf16(ah[ks], bh[nt][ks], acc[nt], 0, 0, 0);
            acc[nt] = __builtin_amdgcn_mfma_f32_16x16x32_bf16(ah[ks], bl[nt][ks], acc[nt], 0, 0, 0);
            acc[nt] = __builtin_amdgcn_mfma_f32_16x16x32_bf16(al[ks], bh[nt][ks], acc[nt], 0, 0, 0);
        }
    }
}

// edge epilogue: neighbor-max + bias + relu -> wave-private h row (identical
// fp32 op order to all prior passing versions).
template <int KP>
__device__ __forceinline__ void edge_epi(const f32x4 acc[4], const float b2v[4],
                                         float* hw, int t2, int lane, int col, int quad)
{
#pragma unroll
    for (int nt = 0; nt < 4; ++nt) {
        float m = fmaxf(fmaxf(acc[nt].x, acc[nt].y), fmaxf(acc[nt].z, acc[nt].w));
        if (KP == 4) {
            const float z = fmaxf(m + b2v[nt], 0.0f);
            hw[(t2 * 4 + quad) * 68 + nt * 16 + col] = z;
        } else {
            m = fmaxf(m, __shfl_xor(m, 16));
            const float z = fmaxf(m + b2v[nt], 0.0f);
            if ((lane & 16) == 0)
                hw[(t2 * 2 + (lane >> 5)) * 68 + nt * 16 + col] = z;
        }
    }
}

// ---------------------------------------------------------------------------
// Kernel 0: pack all five weight matrices into per-lane MFMA B-fragments
// ONCE (exact pack8 bit-sequence).  Layout: see round-13 (verified).
// ---------------------------------------------------------------------------
__global__ __launch_bounds__(256) void packw_kernel(
    const float* __restrict__ w2a, const float* __restrict__ w2b,
    const float* __restrict__ w2c, const float* __restrict__ w1a,
    const float* __restrict__ w1b, char* __restrict__ pw)
{
    const int f = blockIdx.x * 256 + threadIdx.x;
    if (f < 1536) {
        const int m = f >> 9;            // 0..2
        const int f2 = f & 511;
        const int lane = f2 & 63;
        const int ntks = f2 >> 6;        // nt*2+ks
        const int nt = ntks >> 1, ks = ntks & 1;
        const int col = lane & 15, quad = lane >> 4;
        const float* W = (m == 0) ? w2a : (m == 1) ? w2b : w2c;
        float w[8];
#pragma unroll
        for (int j = 0; j < 8; ++j)
            w[j] = W[(size_t)(ks * 32 + quad * 8 + j) * 64 + nt * 16 + col];
        v8s hv, lv; pack8(w, hv, lv);
        ((v8s*)(pw + m * 16384))[f2] = hv;
        ((v8s*)(pw + m * 16384 + 8192))[f2] = lv;
    } else if (f < 3584) {
        const int g = f - 1536;
        const int m = g >> 10;           // 0..1
        const int f2 = g & 1023;
        const int lane = f2 & 63;
        const int r = f2 >> 6;           // half*8 + nt*2 + ks
        const int ks = r & 1, nt = (r >> 1) & 3, half = r >> 3;
        const int col = lane & 15, quad = lane >> 4;
        const float* W = (m == 0) ? w1a : w1b;
        float w[8];
#pragma unroll
        for (int j = 0; j < 8; ++j)
            w[j] = W[(size_t)(half * 64 + ks * 32 + quad * 8 + j) * 64 + nt * 16 + col];
        v8s hv, lv; pack8(w, hv, lv);
        ((v8s*)(pw + 49152 + m * 32768))[f2] = hv;
        ((v8s*)(pw + 49152 + m * 32768 + 16384))[f2] = lv;
    }
}

// ---------------------------------------------------------------------------
// Kernel 1: proven top-6 kNN + fused layer-1 prep tail (round-5 verified).
// ---------------------------------------------------------------------------
__global__ __launch_bounds__(256) void knn6_prep_kernel(
    const float* __restrict__ pos,
    const float* __restrict__ W1, const float* __restrict__ b1,
    int* __restrict__ idx,
    float* __restrict__ Uout, float* __restrict__ Vout)
{
    __shared__ float4 pts[NP];
    __shared__ float  sd[256 * 4];
    __shared__ float  thr[64];
    __shared__ int    ci[256 * 8];
    __shared__ int    cn[256];

    const int blk = blockIdx.x;
    const int b = blk >> 4;
    const int chunk = blk & 15;
    const int t = threadIdx.x;
    const float* gp = pos + (size_t)b * NP * 3;
    for (int q = t; q < NP; q += 256) {
        float x = gp[q * 3 + 0], y = gp[q * 3 + 1], z = gp[q * 3 + 2];
        pts[q] = make_float4(x, y, z, x * x + y * y + z * z);
    }
    __syncthreads();

    const int p = t >> 2;
    const int sub = t & 3;
    const int il = chunk * 64 + p;
    const float4 pi = pts[il];
    const float sqi = pi.w;

    float d0 = 1e30f, d1 = 1e30f, d2v = 1e30f, d3 = 1e30f;
#pragma unroll 4
    for (int it = 0; it < 256; ++it) {
        const int q = (it << 2) | sub;
        const float dq = dist2(pi, sqi, pts[q]);
        d3  = __builtin_amdgcn_fmed3f(dq, d2v, d3);
        d2v = __builtin_amdgcn_fmed3f(dq, d1, d2v);
        d1  = __builtin_amdgcn_fmed3f(dq, d0, d1);
        d0  = fminf(dq, d0);
    }
    {
        float* sp = &sd[t * 4];
        sp[0] = d0; sp[1] = d1; sp[2] = d2v; sp[3] = d3;
    }
    __syncthreads();

    if (t < 64) {
        float e0 = 1e30f, e1 = 1e30f, e2 = 1e30f, e3 = 1e30f, e4 = 1e30f, e5 = 1e30f;
#pragma unroll
        for (int s = 0; s < 4; ++s) {
            const float* q4 = &sd[(t * 4 + s) * 4];
#pragma unroll
            for (int k = 0; k < 4; ++k) {
                const float d = q4[k];
                e5 = __builtin_amdgcn_fmed3f(d, e4, e5);
                e4 = __builtin_amdgcn_fmed3f(d, e3, e4);
                e3 = __builtin_amdgcn_fmed3f(d, e2, e3);
                e2 = __builtin_amdgcn_fmed3f(d, e1, e2);
                e1 = __builtin_amdgcn_fmed3f(d, e0, e1);
                e0 = fminf(d, e0);
            }
        }
        thr[t] = e5;
    }
    __syncthreads();

    const float th = thr[p];
    int cnt = 0;
#pragma unroll 4
    for (int it = 0; it < 256; ++it) {
        const int q = (it << 2) | sub;
        const float dq = dist2(pi, sqi, pts[q]);
        if (dq <= th) {
            ci[t * 8 + (cnt & 7)] = q;
            ++cnt;
        }
    }
    cn[t] = (cnt > 8) ? 8 : cnt;
    __syncthreads();

    if (t < 64) {
        const float4 pit = pts[chunk * 64 + t];
        const float sqit = pit.w;
        float e0 = 1e30f, e1 = 1e30f, e2 = 1e30f, e3 = 1e30f, e4 = 1e30f, e5 = 1e30f;
        int j0 = 0x7fffffff, j1 = 0x7fffffff, j2 = 0x7fffffff,
            j3 = 0x7fffffff, j4 = 0x7fffffff, j5 = 0x7fffffff;
#pragma unroll
        for (int s = 0; s < 4; ++s) {
            const int tid = t * 4 + s;
            const int n = cn[tid];
            for (int e = 0; e < n; ++e) {
                const int q = ci[tid * 8 + e];
                const float d = dist2(pit, sqit, pts[q]);
                if (d < e5 || (d == e5 && q < j5)) {
                    if (d < e4 || (d == e4 && q < j4)) {
                        e5 = e4; j5 = j4;
                        if (d < e3 || (d == e3 && q < j3)) {
                            e4 = e3; j4 = j3;
                            if (d < e2 || (d == e2 && q < j2)) {
                                e3 = e2; j3 = j2;
                                if (d < e1 || (d == e1 && q < j1)) {
                                    e2 = e1; j2 = j1;
                                    if (d < e0 || (d == e0 && q < j0)) {
                                        e1 = e0; j1 = j0; e0 = d; j0 = q;
                                    } else { e1 = d; j1 = q; }
                                } else { e2 = d; j2 = q; }
                            } else { e3 = d; j3 = q; }
                        } else { e4 = d; j4 = q; }
                    } else { e5 = d; j5 = q; }
                }
            }
        }
        const int gb = b * NP;
        int* op = idx + (size_t)(gb + chunk * 64 + t) * 6;
        op[0] = gb + j0; op[1] = gb + j1; op[2] = gb + j2;
        op[3] = gb + j3; op[4] = gb + j4; op[5] = gb + j5;
    }

    // ---- fused prep tail: 64 points x 64 channels (16 per thread) ---------
    {
        const int p2 = t >> 2;
        const int cb = (t & 3) * 16;
        const int il2 = chunk * 64 + p2;
        const float4 pp = pts[il2];
        const size_t gi = (size_t)(b * NP + il2) * 64;
#pragma unroll
        for (int cc = 0; cc < 16; ++cc) {
            const int c = cb + cc;
            float u = b1[c];
            u = fmaf(pp.x, W1[0 * 64 + c] - W1[6 * 64 + c], u);
            u = fmaf(pp.y, W1[1 * 64 + c] - W1[7 * 64 + c], u);
            u = fmaf(pp.z, W1[2 * 64 + c] - W1[8 * 64 + c], u);
            Uout[gi + c] = u;
            float v =      pp.x * (W1[3 * 64 + c] + W1[6 * 64 + c]);
            v = fmaf(pp.y, W1[4 * 64 + c] + W1[7 * 64 + c], v);
            v = fmaf(pp.z, W1[5 * 64 + c] + W1[8 * 64 + c], v);
            Vout[gi + c] = v;
        }
    }
}

// ---------------------------------------------------------------------------
// Kernel 2: FUSED edge(N) + uv(N+1).  Round-13 structure with the edge tile
// loop deepened to a 4-deep software pipeline: 4 tiles' gathers in flight
// (TPW=4 variant issues ALL gathers before any compute).  Same per-tile
// math order -> bit-identical output.
// ---------------------------------------------------------------------------
template <int PT, int KP, int KREAL>
__global__ __launch_bounds__(256, 2) void fused_edge_uv_kernel(
    const float* __restrict__ U, const float* __restrict__ V,
    const int* __restrict__ idx,
    const v8s* __restrict__ w2ph, const v8s* __restrict__ w2pl,
    const float* __restrict__ b2,
    const v8s* __restrict__ w1ph, const v8s* __restrict__ w1pl,
    const float* __restrict__ W1n, const float* __restrict__ b1n,
    const float* __restrict__ pos,
    float* __restrict__ Uout, float* __restrict__ Vout,
    float* __restrict__ pooled_zero)
{
    __shared__ float hlds[4][16 * 68];
    const int t = threadIdx.x;
    const int lane = t & 63;
    const int wv = __builtin_amdgcn_readfirstlane(t >> 6);
    float* hw = &hlds[wv][0];
    const int col = lane & 15;
    const int quad = lane >> 4;
    constexpr int TPW = 16 / PT;   // 8 (PT=2) or 4 (PT=4)

    if (pooled_zero != nullptr && blockIdx.x == 0) {
#pragma unroll
        for (int i = 0; i < 16; ++i) pooled_zero[i * 256 + t] = 0.0f;
    }

    const int x = blockIdx.x & 7;        // XCD slot
    const int r = blockIdx.x >> 3;       // 0..127
    const int g = x * 8 + (r & 7);       // graph
    const int sb = r >> 3;               // 0..15
    const int base16 = g * NP + sb * 64 + wv * 16;   // this wave's 16 points

    // preload ALL 96 neighbor indices for this wave (coalesced, once)
    const int idxa = idx[(size_t)base16 * 6 + lane];
    const int idxb = idx[(size_t)base16 * 6 + 64 + (lane & 31)];

    // ---- edge phase: direct fragments, 4-deep pipelined -------------------
    {
        v8s bh[4][2], bl[4][2];
#pragma unroll
        for (int nt = 0; nt < 4; ++nt) {
#pragma unroll
            for (int ks = 0; ks < 2; ++ks) {
                bh[nt][ks] = w2ph[(nt * 2 + ks) * 64 + lane];
                bl[nt][ks] = w2pl[(nt * 2 + ks) * 64 + lane];
            }
        }
        float b2v[4];
#pragma unroll
        for (int nt = 0; nt < 4; ++nt) b2v[nt] = b2[nt * 16 + col];

#define FETCH(buf, tt) frag_fetch<PT, KP, KREAL>(U, V, idxa, idxb, base16, tt, lane, buf)
#define TILE(buf, t2c) { v8s ah[2], al[2]; frag_pack(buf, ah, al); \
        f32x4 acc[4]; edge_mfma(ah, al, bh, bl, acc); \
        edge_epi<KP>(acc, b2v, hw, t2c, lane, col, quad); }

        float4 rA[8], rB[8], rC[8], rD[8];
        FETCH(rA, 0); FETCH(rB, 1); FETCH(rC, 2); FETCH(rD, 3);
        if constexpr (TPW == 8) {
            TILE(rA, 0); FETCH(rA, 4);
            TILE(rB, 1); FETCH(rB, 5);
            TILE(rC, 2); FETCH(rC, 6);
            TILE(rD, 3); FETCH(rD, 7);
            TILE(rA, 4); TILE(rB, 5); TILE(rC, 6); TILE(rD, 7);
        } else {
            TILE(rA, 0); TILE(rB, 1); TILE(rC, 2); TILE(rD, 3);
        }
#undef FETCH
#undef TILE
    }
    __builtin_amdgcn_wave_barrier();
    __builtin_amdgcn_s_waitcnt(0xc07f);   // h rows visible to this wave

    // ---- uv phase: [U'|V'] = h @ [W1n_a|W1n_b] ----------------------------
    v8s ah[2], al[2];
#pragma unroll
    for (int ks = 0; ks < 2; ++ks) {
        float w[8];
        const float4 f0 = *(const float4*)(hw + col * 68 + ks * 32 + quad * 8);
        const float4 f1 = *(const float4*)(hw + col * 68 + ks * 32 + quad * 8 + 4);
        w[0] = f0.x; w[1] = f0.y; w[2] = f0.z; w[3] = f0.w;
        w[4] = f1.x; w[5] = f1.y; w[6] = f1.z; w[7] = f1.w;
        pack8(w, ah[ks], al[ks]);
    }

    float prx[4], pry[4], prz[4];
#pragma unroll
    for (int r2 = 0; r2 < 4; ++r2) {
        const int pt = base16 + quad * 4 + r2;
        prx[r2] = pos[pt * 3 + 0];
        pry[r2] = pos[pt * 3 + 1];
        prz[r2] = pos[pt * 3 + 2];
    }
    float wcx[4], wcy[4], wcz[4], b1v[4];
#pragma unroll
    for (int nt = 0; nt < 4; ++nt) {
        wcx[nt] = W1n[128 * 64 + nt * 16 + col];
        wcy[nt] = W1n[129 * 64 + nt * 16 + col];
        wcz[nt] = W1n[130 * 64 + nt * 16 + col];
        b1v[nt] = b1n[nt * 16 + col];
    }

    for (int half = 1; half >= 0; --half) {
        v8s bh2[4][2], bl2[4][2];
#pragma unroll
        for (int nt = 0; nt < 4; ++nt) {
#pragma unroll
            for (int ks = 0; ks < 2; ++ks) {
                bh2[nt][ks] = w1ph[(half * 8 + nt * 2 + ks) * 64 + lane];
                bl2[nt][ks] = w1pl[(half * 8 + nt * 2 + ks) * 64 + lane];
            }
        }

        f32x4 acc[4];
#pragma unroll
        for (int nt = 0; nt < 4; ++nt) acc[nt] = (f32x4){0.f, 0.f, 0.f, 0.f};
#pragma unroll
        for (int nt = 0; nt < 4; ++nt) {
#pragma unroll
            for (int ks = 0; ks < 2; ++ks) {
                acc[nt] = __builtin_amdgcn_mfma_f32_16x16x32_bf16(ah[ks], bh2[nt][ks], acc[nt], 0, 0, 0);
                acc[nt] = __builtin_amdgcn_mfma_f32_16x16x32_bf16(ah[ks], bl2[nt][ks], acc[nt], 0, 0, 0);
                acc[nt] = __builtin_amdgcn_mfma_f32_16x16x32_bf16(al[ks], bh2[nt][ks], acc[nt], 0, 0, 0);
            }
        }

        float* outp = half ? Vout : Uout;
#pragma unroll
        for (int nt = 0; nt < 4; ++nt) {
            const float* a = (const float*)&acc[nt];
#pragma unroll
            for (int r2 = 0; r2 < 4; ++r2) {
                float dotp = fmaf(prz[r2], wcz[nt], fmaf(pry[r2], wcy[nt], prx[r2] * wcx[nt]));
                float val = half ? (a[r2] + dotp) : (a[r2] + b1v[nt] - dotp);
                outp[(size_t)(base16 + quad * 4 + r2) * 64 + nt * 16 + col] = val;
            }
        }
    }
}

// ---------------------------------------------------------------------------
// Kernel 3: final edge layer (TPW=2: already full-depth pipelined);
// pre-packed W2 fragments; pool-max in registers.
// ---------------------------------------------------------------------------
template <int PT, int KP, int KREAL, int TPW>
__global__ __launch_bounds__(256, 2) void edge3_mfma_kernel(
    const float* __restrict__ U, const float* __restrict__ V,
    const int* __restrict__ idx,
    const v8s* __restrict__ w2ph, const v8s* __restrict__ w2pl,
    const float* __restrict__ b2,
    float* __restrict__ outp)
{
    const int t = threadIdx.x;
    const int lane = t & 63;
    const int wv = __builtin_amdgcn_readfirstlane(t >> 6);
    const int col = lane & 15;
    const int quad = lane >> 4;

    const int x = blockIdx.x & 7;
    const int r = blockIdx.x >> 3;
    const int g = x * 8 + (r & 7);
    const int sb = r >> 3;
    const int pbase = g * NP + (sb * 4 + wv) * (PT * TPW);   // 8 consecutive points

    // preload the 48 neighbor indices for this wave (li <= 45 -> idxa only)
    const int idxa = idx[(size_t)pbase * 6 + lane];

    v8s bh[4][2], bl[4][2];
#pragma unroll
    for (int nt = 0; nt < 4; ++nt) {
#pragma unroll
        for (int ks = 0; ks < 2; ++ks) {
            bh[nt][ks] = w2ph[(nt * 2 + ks) * 64 + lane];
            bl[nt][ks] = w2pl[(nt * 2 + ks) * 64 + lane];
        }
    }
    float b2v[4];
#pragma unroll
    for (int nt = 0; nt < 4; ++nt) b2v[nt] = b2[nt * 16 + col];

    float zacc[4] = {0.f, 0.f, 0.f, 0.f};   // relu'd values are >= 0

    float4 r0[8], r1[8];
    frag_fetch<PT, KP, KREAL>(U, V, idxa, idxa, pbase, 0, lane, r0);
    frag_fetch<PT, KP, KREAL>(U, V, idxa, idxa, pbase, 1, lane, r1);
    {
        v8s ah[2], al[2];
        frag_pack(r0, ah, al);
        f32x4 acc[4];
        edge_mfma(ah, al, bh, bl, acc);
#pragma unroll
        for (int nt = 0; nt < 4; ++nt) {
            float m = fmaxf(fmaxf(acc[nt].x, acc[nt].y), fmaxf(acc[nt].z, acc[nt].w));
            zacc[nt] = fmaxf(zacc[nt], fmaxf(m + b2v[nt], 0.0f));
        }
    }
    {
        v8s ah[2], al[2];
        frag_pack(r1, ah, al);
        f32x4 acc[4];
        edge_mfma(ah, al, bh, bl, acc);
#pragma unroll
        for (int nt = 0; nt < 4; ++nt) {
            float m = fmaxf(fmaxf(acc[nt].x, acc[nt].y), fmaxf(acc[nt].z, acc[nt].w));
            zacc[nt] = fmaxf(zacc[nt], fmaxf(m + b2v[nt], 0.0f));
        }
    }

#pragma unroll
    for (int nt = 0; nt < 4; ++nt) {
        float zm = fmaxf(zacc[nt], __shfl_xor(zacc[nt], 16));
        zm = fmaxf(zm, __shfl_xor(zm, 32));
        if (quad == 0) {
            atomicMax((unsigned int*)(outp + (size_t)g * 64 + nt * 16 + col),
                      __float_as_uint(zm));
        }
    }
}

// ---------------------------------------------------------------------------
// Kernel 4: final 64->6 regression from pooled. 6 blocks x 64 threads.
// ---------------------------------------------------------------------------
__global__ __launch_bounds__(64) void reg_kernel(
    const float* __restrict__ pooled, const float* __restrict__ regW,
    const float* __restrict__ regb, float* __restrict__ out)
{
    const int t = blockIdx.x * 64 + threadIdx.x;
    const int b = t / 6;
    const int o = t - b * 6;
    if (t < NB * 6) {
        float z = regb[o];
        const float* pb = pooled + (size_t)b * 64;
        for (int c = 0; c < 64; ++c) z = fmaf(pb[c], regW[c * 6 + o], z);
        out[b * 6 + o] = z;
    }
}

// ---------------------------------------------------------------------------
extern "C" void kernel_launch(void* const* d_in, const int* in_sizes, int n_in,
                              void* d_out, int out_size, void* d_ws, size_t ws_size,
                              hipStream_t stream)
{
    (void)in_sizes; (void)n_in; (void)out_size; (void)ws_size;
    const float* pos   = (const float*)d_in[1];
    const float* c1W1  = (const float*)d_in[3];
    const float* c1b1  = (const float*)d_in[4];
    const float* c1W2  = (const float*)d_in[5];
    const float* c1b2  = (const float*)d_in[6];
    const float* c2W1  = (const float*)d_in[7];
    const float* c2b1  = (const float*)d_in[8];
    const float* c2W2  = (const float*)d_in[9];
    const float* c2b2  = (const float*)d_in[10];
    const float* c3W1  = (const float*)d_in[11];
    const float* c3b1  = (const float*)d_in[12];
    const float* c3W2  = (const float*)d_in[13];
    const float* c3b2  = (const float*)d_in[14];
    const float* regW  = (const float*)d_in[15];
    const float* regb  = (const float*)d_in[16];
    float* out = (float*)d_out;

    // workspace: idx | A | C | D | E | pooled | packed-weights (112 KB)
    char* ws = (char*)d_ws;
    int*   idx = (int*)ws;                                    // 1.5 MB
    float* A = (float*)(ws + 1572864);
    float* C = (float*)(ws + 1572864 + 1 * 16777216);
    float* D = (float*)(ws + 1572864 + 2 * 16777216);
    float* E = (float*)(ws + 1572864 + 3 * 16777216);
    float* pooled = (float*)(ws + 1572864 + 4 * 16777216);    // 16 KB
    char*  pw = ws + 1572864 + 4 * 16777216 + 16384;
    const v8s* c1W2ph = (const v8s*)(pw);
    const v8s* c1W2pl = (const v8s*)(pw + 8192);
    const v8s* c2W2ph = (const v8s*)(pw + 16384);
    const v8s* c2W2pl = (const v8s*)(pw + 24576);
    const v8s* c3W2ph = (const v8s*)(pw + 32768);
    const v8s* c3W2pl = (const v8s*)(pw + 40960);
    const v8s* c2W1ph = (const v8s*)(pw + 49152);
    const v8s* c2W1pl = (const v8s*)(pw + 65536);
    const v8s* c3W1ph = (const v8s*)(pw + 81920);
    const v8s* c3W1pl = (const v8s*)(pw + 98304);

    // pack all weight fragments once (tiny)
    packw_kernel<<<14, 256, 0, stream>>>(c1W2, c2W2, c3W2, c2W1, c3W1, pw);

    // kNN + layer-1 prep (U1 -> D, Vpos -> C) in one launch
    knn6_prep_kernel<<<NB * 16, 256, 0, stream>>>(pos, c1W1, c1b1, idx, D, C);

    // fused layer1-edge + layer2-uv: reads (D=U1, C=Vpos) -> U2->A, V2->E
    fused_edge_uv_kernel<2, 8, 6><<<1024, 256, 0, stream>>>(
        D, C, idx, c1W2ph, c1W2pl, c1b2, c2W1ph, c2W1pl, c2W1, c2b1, pos,
        A, E, nullptr);

    // fused layer2-edge + layer3-uv: reads (A=U2, E=V2) -> U3->D, V3->C
    // (block 0 zeroes pooled)
    fused_edge_uv_kernel<4, 4, 4><<<1024, 256, 0, stream>>>(
        A, E, idx, c2W2ph, c2W2pl, c2b2, c3W1ph, c3W1pl, c3W1, c3b1, pos,
        D, C, pooled);

    // layer3 edge -> atomic max into pooled
    edge3_mfma_kernel<4, 4, 3, 2><<<2048, 256, 0, stream>>>(
        D, C, idx, c3W2ph, c3W2pl, c3b2, pooled);

    // final regression
    reg_kernel<<<6, 64, 0, stream>>>(pooled, regW, regb, out);
}

// Round 15
// 209.601 us; speedup vs baseline: 1.0399x; 1.0399x over previous
//
#include <hip/hip_runtime.h>
#include <cstddef>

#define NB 64
#define NP 1024
#define NPTS (NB * NP)

typedef __attribute__((ext_vector_type(8))) short v8s;
typedef __attribute__((ext_vector_type(4))) float f32x4;

__device__ __forceinline__ float dist2(const float4 pi, const float sqi, const float4 pq) {
    const float dot = fmaf(pi.z, pq.z, fmaf(pi.y, pq.y, pi.x * pq.x));
    return fmaf(-2.0f, dot, sqi + pq.w);
}

__device__ __forceinline__ void pack8(const float* w, v8s& hv, v8s& lv) {
    union { v8s v; unsigned int u[4]; } H, L;
#pragma unroll
    for (int p = 0; p < 4; ++p) {
        unsigned int a = __float_as_uint(w[2 * p]);
        unsigned int b = __float_as_uint(w[2 * p + 1]);
        unsigned int ha = a & 0xffff0000u, hb = b & 0xffff0000u;
        H.u[p] = (ha >> 16) | hb;
        float la = w[2 * p] - __uint_as_float(ha);
        float lb = w[2 * p + 1] - __uint_as_float(hb);
        L.u[p] = (__float_as_uint(la) >> 16) | (__float_as_uint(lb) & 0xffff0000u);
    }
    hv = H.v; lv = L.v;
}

// ---------------------------------------------------------------------------
// Direct A-fragment path (round-11/12 verified):
//  - j from wave-preloaded idxa/idxb via ds_bpermute (no per-tile VMEM)
//  - raw row slices fetched into 8 float4 regs (2-deep pipelined by caller)
//  - pack applies the EXACT add/relu/hi-lo split -> bit-identical values
// ---------------------------------------------------------------------------
template <int PT, int KP, int KREAL>
__device__ __forceinline__ void frag_fetch(
    const float* __restrict__ U, const float* __restrict__ V,
    int idxa, int idxb, int pb0, int tt, int lane, float4 r[8])
{
    constexpr int KSH = (KP == 8) ? 3 : 2;
    const int er = lane & 15;            // this lane's edge row
    const int quad = lane >> 4;          // 8-channel slice
    const int p = er >> KSH;
    int k = er & (KP - 1);
    if (k >= KREAL) k = 0;               // duplicate-k rows reuse the k=0 row
    const int li = (tt * PT + p) * 6 + k;
    const int ja = __builtin_amdgcn_ds_bpermute(li << 2, idxa);
    const int jb = __builtin_amdgcn_ds_bpermute(((li - 64) & 63) << 2, idxb);
    const int j = (li < 64) ? ja : jb;
    const int pt = pb0 + tt * PT + p;
    const float* vrow = V + (size_t)j * 64 + quad * 8;
    const float* urow = U + (size_t)pt * 64 + quad * 8;
    r[0] = *(const float4*)(vrow + 0);
    r[1] = *(const float4*)(vrow + 4);
    r[2] = *(const float4*)(vrow + 32);
    r[3] = *(const float4*)(vrow + 36);
    r[4] = *(const float4*)(urow + 0);
    r[5] = *(const float4*)(urow + 4);
    r[6] = *(const float4*)(urow + 32);
    r[7] = *(const float4*)(urow + 36);
}

__device__ __forceinline__ void frag_pack(const float4 r[8], v8s ah[2], v8s al[2])
{
#pragma unroll
    for (int ks = 0; ks < 2; ++ks) {
        const float4 v0 = r[ks * 2 + 0], v1 = r[ks * 2 + 1];
        const float4 u0 = r[4 + ks * 2 + 0], u1 = r[4 + ks * 2 + 1];
        float w[8];
        w[0] = fmaxf(u0.x + v0.x, 0.0f);
        w[1] = fmaxf(u0.y + v0.y, 0.0f);
        w[2] = fmaxf(u0.z + v0.z, 0.0f);
        w[3] = fmaxf(u0.w + v0.w, 0.0f);
        w[4] = fmaxf(u1.x + v1.x, 0.0f);
        w[5] = fmaxf(u1.y + v1.y, 0.0f);
        w[6] = fmaxf(u1.z + v1.z, 0.0f);
        w[7] = fmaxf(u1.w + v1.w, 0.0f);
        pack8(w, ah[ks], al[ks]);
    }
}

// 24-MFMA edge tile (same acc order as all prior passing versions).
__device__ __forceinline__ void edge_mfma(const v8s ah[2], const v8s al[2],
                                          const v8s bh[4][2], const v8s bl[4][2],
                                          f32x4 acc[4])
{
#pragma unroll
    for (int nt = 0; nt < 4; ++nt) acc[nt] = (f32x4){0.f, 0.f, 0.f, 0.f};
#pragma unroll
    for (int nt = 0; nt < 4; ++nt) {
#pragma unroll
        for (int ks = 0; ks < 2; ++ks) {
            acc[nt] = __builtin_amdgcn_mfma_f32_16x16x32_bf16(ah[ks], bh[nt][ks], acc[nt], 0, 0, 0);
            acc[nt] = __builtin_amdgcn_mfma_f32_16x16x32_bf16(ah[ks], bl[nt][ks], acc[nt], 0, 0, 0);
            acc[nt] = __builtin_amdgcn_mfma_f32_16x16x32_bf16(al[ks], bh[nt][ks], acc[nt], 0, 0, 0);
        }
    }
}

// ---------------------------------------------------------------------------
// Kernel 0: pack all five weight matrices into per-lane MFMA B-fragments
// ONCE (the exact pack8 bit-sequence every wave used to run privately).
// Layout per matrix: PH array of v8s indexed [(frag)*64 + lane] (coalesced),
// PL array after it.  W2-type: 512 frags (8KB each).  W1n-type: 1024 (16KB).
// pw byte map: c1W2@0, c2W2@16K, c3W2@32K, c2W1@48K(+32K), c3W1@80K(+32K).
// ---------------------------------------------------------------------------
__global__ __launch_bounds__(256) void packw_kernel(
    const float* __restrict__ w2a, const float* __restrict__ w2b,
    const float* __restrict__ w2c, const float* __restrict__ w1a,
    const float* __restrict__ w1b, char* __restrict__ pw)
{
    const int f = blockIdx.x * 256 + threadIdx.x;
    if (f < 1536) {
        const int m = f >> 9;            // 0..2
        const int f2 = f & 511;
        const int lane = f2 & 63;
        const int ntks = f2 >> 6;        // nt*2+ks
        const int nt = ntks >> 1, ks = ntks & 1;
        const int col = lane & 15, quad = lane >> 4;
        const float* W = (m == 0) ? w2a : (m == 1) ? w2b : w2c;
        float w[8];
#pragma unroll
        for (int j = 0; j < 8; ++j)
            w[j] = W[(size_t)(ks * 32 + quad * 8 + j) * 64 + nt * 16 + col];
        v8s hv, lv; pack8(w, hv, lv);
        ((v8s*)(pw + m * 16384))[f2] = hv;
        ((v8s*)(pw + m * 16384 + 8192))[f2] = lv;
    } else if (f < 3584) {
        const int g = f - 1536;
        const int m = g >> 10;           // 0..1
        const int f2 = g & 1023;
        const int lane = f2 & 63;
        const int r = f2 >> 6;           // half*8 + nt*2 + ks
        const int ks = r & 1, nt = (r >> 1) & 3, half = r >> 3;
        const int col = lane & 15, quad = lane >> 4;
        const float* W = (m == 0) ? w1a : w1b;
        float w[8];
#pragma unroll
        for (int j = 0; j < 8; ++j)
            w[j] = W[(size_t)(half * 64 + ks * 32 + quad * 8 + j) * 64 + nt * 16 + col];
        v8s hv, lv; pack8(w, hv, lv);
        ((v8s*)(pw + 49152 + m * 32768))[f2] = hv;
        ((v8s*)(pw + 49152 + m * 32768 + 16384))[f2] = lv;
    }
}

// ---------------------------------------------------------------------------
// Kernel 1: proven top-6 kNN + fused layer-1 prep tail (round-5 verified).
// ---------------------------------------------------------------------------
__global__ __launch_bounds__(256) void knn6_prep_kernel(
    const float* __restrict__ pos,
    const float* __restrict__ W1, const float* __restrict__ b1,
    int* __restrict__ idx,
    float* __restrict__ Uout, float* __restrict__ Vout)
{
    __shared__ float4 pts[NP];
    __shared__ float  sd[256 * 4];
    __shared__ float  thr[64];
    __shared__ int    ci[256 * 8];
    __shared__ int    cn[256];

    const int blk = blockIdx.x;
    const int b = blk >> 4;
    const int chunk = blk & 15;
    const int t = threadIdx.x;
    const float* gp = pos + (size_t)b * NP * 3;
    for (int q = t; q < NP; q += 256) {
        float x = gp[q * 3 + 0], y = gp[q * 3 + 1], z = gp[q * 3 + 2];
        pts[q] = make_float4(x, y, z, x * x + y * y + z * z);
    }
    __syncthreads();

    const int p = t >> 2;
    const int sub = t & 3;
    const int il = chunk * 64 + p;
    const float4 pi = pts[il];
    const float sqi = pi.w;

    float d0 = 1e30f, d1 = 1e30f, d2v = 1e30f, d3 = 1e30f;
#pragma unroll 4
    for (int it = 0; it < 256; ++it) {
        const int q = (it << 2) | sub;
        const float dq = dist2(pi, sqi, pts[q]);
        d3  = __builtin_amdgcn_fmed3f(dq, d2v, d3);
        d2v = __builtin_amdgcn_fmed3f(dq, d1, d2v);
        d1  = __builtin_amdgcn_fmed3f(dq, d0, d1);
        d0  = fminf(dq, d0);
    }
    {
        float* sp = &sd[t * 4];
        sp[0] = d0; sp[1] = d1; sp[2] = d2v; sp[3] = d3;
    }
    __syncthreads();

    if (t < 64) {
        float e0 = 1e30f, e1 = 1e30f, e2 = 1e30f, e3 = 1e30f, e4 = 1e30f, e5 = 1e30f;
#pragma unroll
        for (int s = 0; s < 4; ++s) {
            const float* q4 = &sd[(t * 4 + s) * 4];
#pragma unroll
            for (int k = 0; k < 4; ++k) {
                const float d = q4[k];
                e5 = __builtin_amdgcn_fmed3f(d, e4, e5);
                e4 = __builtin_amdgcn_fmed3f(d, e3, e4);
                e3 = __builtin_amdgcn_fmed3f(d, e2, e3);
                e2 = __builtin_amdgcn_fmed3f(d, e1, e2);
                e1 = __builtin_amdgcn_fmed3f(d, e0, e1);
                e0 = fminf(d, e0);
            }
        }
        thr[t] = e5;
    }
    __syncthreads();

    const float th = thr[p];
    int cnt = 0;
#pragma unroll 4
    for (int it = 0; it < 256; ++it) {
        const int q = (it << 2) | sub;
        const float dq = dist2(pi, sqi, pts[q]);
        if (dq <= th) {
            ci[t * 8 + (cnt & 7)] = q;
            ++cnt;
        }
    }
    cn[t] = (cnt > 8) ? 8 : cnt;
    __syncthreads();

    if (t < 64) {
        const float4 pit = pts[chunk * 64 + t];
        const float sqit = pit.w;
        float e0 = 1e30f, e1 = 1e30f, e2 = 1e30f, e3 = 1e30f, e4 = 1e30f, e5 = 1e30f;
        int j0 = 0x7fffffff, j1 = 0x7fffffff, j2 = 0x7fffffff,
            j3 = 0x7fffffff, j4 = 0x7fffffff, j5 = 0x7fffffff;
#pragma unroll
        for (int s = 0; s < 4; ++s) {
            const int tid = t * 4 + s;
            const int n = cn[tid];
            for (int e = 0; e < n; ++e) {
                const int q = ci[tid * 8 + e];
                const float d = dist2(pit, sqit, pts[q]);
                if (d < e5 || (d == e5 && q < j5)) {
                    if (d < e4 || (d == e4 && q < j4)) {
                        e5 = e4; j5 = j4;
                        if (d < e3 || (d == e3 && q < j3)) {
                            e4 = e3; j4 = j3;
                            if (d < e2 || (d == e2 && q < j2)) {
                                e3 = e2; j3 = j2;
                                if (d < e1 || (d == e1 && q < j1)) {
                                    e2 = e1; j2 = j1;
                                    if (d < e0 || (d == e0 && q < j0)) {
                                        e1 = e0; j1 = j0; e0 = d; j0 = q;
                                    } else { e1 = d; j1 = q; }
                                } else { e2 = d; j2 = q; }
                            } else { e3 = d; j3 = q; }
                        } else { e4 = d; j4 = q; }
                    } else { e5 = d; j5 = q; }
                }
            }
        }
        const int gb = b * NP;
        int* op = idx + (size_t)(gb + chunk * 64 + t) * 6;
        op[0] = gb + j0; op[1] = gb + j1; op[2] = gb + j2;
        op[3] = gb + j3; op[4] = gb + j4; op[5] = gb + j5;
    }

    // ---- fused prep tail: 64 points x 64 channels (16 per thread) ---------
    {
        const int p2 = t >> 2;
        const int cb = (t & 3) * 16;
        const int il2 = chunk * 64 + p2;
        const float4 pp = pts[il2];
        const size_t gi = (size_t)(b * NP + il2) * 64;
#pragma unroll
        for (int cc = 0; cc < 16; ++cc) {
            const int c = cb + cc;
            float u = b1[c];
            u = fmaf(pp.x, W1[0 * 64 + c] - W1[6 * 64 + c], u);
            u = fmaf(pp.y, W1[1 * 64 + c] - W1[7 * 64 + c], u);
            u = fmaf(pp.z, W1[2 * 64 + c] - W1[8 * 64 + c], u);
            Uout[gi + c] = u;
            float v =      pp.x * (W1[3 * 64 + c] + W1[6 * 64 + c]);
            v = fmaf(pp.y, W1[4 * 64 + c] + W1[7 * 64 + c], v);
            v = fmaf(pp.z, W1[5 * 64 + c] + W1[8 * 64 + c], v);
            Vout[gi + c] = v;
        }
    }
}

// ---------------------------------------------------------------------------
// Kernel 2: FUSED edge(N) + uv(N+1).  Round-12 structure; B-fragments
// LOADED pre-packed (1 dwordx4 each); 2-deep tile pipeline (the proven
// best configuration of this session: 210.9us total).
// ---------------------------------------------------------------------------
template <int PT, int KP, int KREAL>
__global__ __launch_bounds__(256, 2) void fused_edge_uv_kernel(
    const float* __restrict__ U, const float* __restrict__ V,
    const int* __restrict__ idx,
    const v8s* __restrict__ w2ph, const v8s* __restrict__ w2pl,
    const float* __restrict__ b2,
    const v8s* __restrict__ w1ph, const v8s* __restrict__ w1pl,
    const float* __restrict__ W1n, const float* __restrict__ b1n,
    const float* __restrict__ pos,
    float* __restrict__ Uout, float* __restrict__ Vout,
    float* __restrict__ pooled_zero)
{
    __shared__ float hlds[4][16 * 68];
    const int t = threadIdx.x;
    const int lane = t & 63;
    const int wv = __builtin_amdgcn_readfirstlane(t >> 6);
    float* hw = &hlds[wv][0];
    const int col = lane & 15;
    const int quad = lane >> 4;
    constexpr int TPW = 16 / PT;

    if (pooled_zero != nullptr && blockIdx.x == 0) {
#pragma unroll
        for (int i = 0; i < 16; ++i) pooled_zero[i * 256 + t] = 0.0f;
    }

    const int x = blockIdx.x & 7;        // XCD slot
    const int r = blockIdx.x >> 3;       // 0..127
    const int g = x * 8 + (r & 7);       // graph
    const int sb = r >> 3;               // 0..15
    const int base16 = g * NP + sb * 64 + wv * 16;   // this wave's 16 points

    // preload ALL 96 neighbor indices for this wave (coalesced, once)
    const int idxa = idx[(size_t)base16 * 6 + lane];
    const int idxb = idx[(size_t)base16 * 6 + 64 + (lane & 31)];

    // ---- edge phase: direct fragments, 2-deep pipelined -------------------
    {
        v8s bh[4][2], bl[4][2];
#pragma unroll
        for (int nt = 0; nt < 4; ++nt) {
#pragma unroll
            for (int ks = 0; ks < 2; ++ks) {
                bh[nt][ks] = w2ph[(nt * 2 + ks) * 64 + lane];
                bl[nt][ks] = w2pl[(nt * 2 + ks) * 64 + lane];
            }
        }
        float b2v[4];
#pragma unroll
        for (int nt = 0; nt < 4; ++nt) b2v[nt] = b2[nt * 16 + col];

        float4 r0[8], r1[8];
        frag_fetch<PT, KP, KREAL>(U, V, idxa, idxb, base16, 0, lane, r0);

#pragma unroll
        for (int t2 = 0; t2 < TPW; t2 += 2) {
            if (t2 + 1 < TPW)
                frag_fetch<PT, KP, KREAL>(U, V, idxa, idxb, base16, t2 + 1, lane, r1);
            {
                v8s ah[2], al[2];
                frag_pack(r0, ah, al);
                f32x4 acc[4];
                edge_mfma(ah, al, bh, bl, acc);
#pragma unroll
                for (int nt = 0; nt < 4; ++nt) {
                    float m = fmaxf(fmaxf(acc[nt].x, acc[nt].y), fmaxf(acc[nt].z, acc[nt].w));
                    if (KP == 4) {
                        const float z = fmaxf(m + b2v[nt], 0.0f);
                        hw[(t2 * 4 + quad) * 68 + nt * 16 + col] = z;
                    } else {
                        m = fmaxf(m, __shfl_xor(m, 16));
                        const float z = fmaxf(m + b2v[nt], 0.0f);
                        if ((lane & 16) == 0)
                            hw[(t2 * 2 + (lane >> 5)) * 68 + nt * 16 + col] = z;
                    }
                }
            }
            if (t2 + 1 < TPW) {
                if (t2 + 2 < TPW)
                    frag_fetch<PT, KP, KREAL>(U, V, idxa, idxb, base16, t2 + 2, lane, r0);
                v8s ah[2], al[2];
                frag_pack(r1, ah, al);
                f32x4 acc[4];
                edge_mfma(ah, al, bh, bl, acc);
#pragma unroll
                for (int nt = 0; nt < 4; ++nt) {
                    float m = fmaxf(fmaxf(acc[nt].x, acc[nt].y), fmaxf(acc[nt].z, acc[nt].w));
                    if (KP == 4) {
                        const float z = fmaxf(m + b2v[nt], 0.0f);
                        hw[((t2 + 1) * 4 + quad) * 68 + nt * 16 + col] = z;
                    } else {
                        m = fmaxf(m, __shfl_xor(m, 16));
                        const float z = fmaxf(m + b2v[nt], 0.0f);
                        if ((lane & 16) == 0)
                            hw[((t2 + 1) * 2 + (lane >> 5)) * 68 + nt * 16 + col] = z;
                    }
                }
            }
        }
    }
    __builtin_amdgcn_wave_barrier();
    __builtin_amdgcn_s_waitcnt(0xc07f);   // h rows visible to this wave

    // ---- uv phase: [U'|V'] = h @ [W1n_a|W1n_b] ----------------------------
    v8s ah[2], al[2];
#pragma unroll
    for (int ks = 0; ks < 2; ++ks) {
        float w[8];
        const float4 f0 = *(const float4*)(hw + col * 68 + ks * 32 + quad * 8);
        const float4 f1 = *(const float4*)(hw + col * 68 + ks * 32 + quad * 8 + 4);
        w[0] = f0.x; w[1] = f0.y; w[2] = f0.z; w[3] = f0.w;
        w[4] = f1.x; w[5] = f1.y; w[6] = f1.z; w[7] = f1.w;
        pack8(w, ah[ks], al[ks]);
    }

    float prx[4], pry[4], prz[4];
#pragma unroll
    for (int r2 = 0; r2 < 4; ++r2) {
        const int pt = base16 + quad * 4 + r2;
        prx[r2] = pos[pt * 3 + 0];
        pry[r2] = pos[pt * 3 + 1];
        prz[r2] = pos[pt * 3 + 2];
    }
    float wcx[4], wcy[4], wcz[4], b1v[4];
#pragma unroll
    for (int nt = 0; nt < 4; ++nt) {
        wcx[nt] = W1n[128 * 64 + nt * 16 + col];
        wcy[nt] = W1n[129 * 64 + nt * 16 + col];
        wcz[nt] = W1n[130 * 64 + nt * 16 + col];
        b1v[nt] = b1n[nt * 16 + col];
    }

    for (int half = 1; half >= 0; --half) {
        v8s bh2[4][2], bl2[4][2];
#pragma unroll
        for (int nt = 0; nt < 4; ++nt) {
#pragma unroll
            for (int ks = 0; ks < 2; ++ks) {
                bh2[nt][ks] = w1ph[(half * 8 + nt * 2 + ks) * 64 + lane];
                bl2[nt][ks] = w1pl[(half * 8 + nt * 2 + ks) * 64 + lane];
            }
        }

        f32x4 acc[4];
#pragma unroll
        for (int nt = 0; nt < 4; ++nt) acc[nt] = (f32x4){0.f, 0.f, 0.f, 0.f};
#pragma unroll
        for (int nt = 0; nt < 4; ++nt) {
#pragma unroll
            for (int ks = 0; ks < 2; ++ks) {
                acc[nt] = __builtin_amdgcn_mfma_f32_16x16x32_bf16(ah[ks], bh2[nt][ks], acc[nt], 0, 0, 0);
                acc[nt] = __builtin_amdgcn_mfma_f32_16x16x32_bf16(ah[ks], bl2[nt][ks], acc[nt], 0, 0, 0);
                acc[nt] = __builtin_amdgcn_mfma_f32_16x16x32_bf16(al[ks], bh2[nt][ks], acc[nt], 0, 0, 0);
            }
        }

        float* outp = half ? Vout : Uout;
#pragma unroll
        for (int nt = 0; nt < 4; ++nt) {
            const float* a = (const float*)&acc[nt];
#pragma unroll
            for (int r2 = 0; r2 < 4; ++r2) {
                float dotp = fmaf(prz[r2], wcz[nt], fmaf(pry[r2], wcy[nt], prx[r2] * wcx[nt]));
                float val = half ? (a[r2] + dotp) : (a[r2] + b1v[nt] - dotp);
                outp[(size_t)(base16 + quad * 4 + r2) * 64 + nt * 16 + col] = val;
            }
        }
    }
}

// ---------------------------------------------------------------------------
// Kernel 3: final edge layer, direct fragments + preloaded idx + 2-deep
// pipeline; pre-packed W2 fragments; pool-max in registers.
// ---------------------------------------------------------------------------
template <int PT, int KP, int KREAL, int TPW>
__global__ __launch_bounds__(256, 2) void edge3_mfma_kernel(
    const float* __restrict__ U, const float* __restrict__ V,
    const int* __restrict__ idx,
    const v8s* __restrict__ w2ph, const v8s* __restrict__ w2pl,
    const float* __restrict__ b2,
    float* __restrict__ outp)
{
    const int t = threadIdx.x;
    const int lane = t & 63;
    const int wv = __builtin_amdgcn_readfirstlane(t >> 6);
    const int col = lane & 15;
    const int quad = lane >> 4;

    const int x = blockIdx.x & 7;
    const int r = blockIdx.x >> 3;
    const int g = x * 8 + (r & 7);
    const int sb = r >> 3;
    const int pbase = g * NP + (sb * 4 + wv) * (PT * TPW);   // 8 consecutive points

    // preload the 48 neighbor indices for this wave (li <= 45 -> idxa only)
    const int idxa = idx[(size_t)pbase * 6 + lane];

    v8s bh[4][2], bl[4][2];
#pragma unroll
    for (int nt = 0; nt < 4; ++nt) {
#pragma unroll
        for (int ks = 0; ks < 2; ++ks) {
            bh[nt][ks] = w2ph[(nt * 2 + ks) * 64 + lane];
            bl[nt][ks] = w2pl[(nt * 2 + ks) * 64 + lane];
        }
    }
    float b2v[4];
#pragma unroll
    for (int nt = 0; nt < 4; ++nt) b2v[nt] = b2[nt * 16 + col];

    float zacc[4] = {0.f, 0.f, 0.f, 0.f};   // relu'd values are >= 0

    float4 r0[8], r1[8];
    frag_fetch<PT, KP, KREAL>(U, V, idxa, idxa, pbase, 0, lane, r0);

#pragma unroll
    for (int t2 = 0; t2 < TPW; t2 += 2) {
        if (t2 + 1 < TPW)
            frag_fetch<PT, KP, KREAL>(U, V, idxa, idxa, pbase, t2 + 1, lane, r1);
        {
            v8s ah[2], al[2];
            frag_pack(r0, ah, al);
            f32x4 acc[4];
            edge_mfma(ah, al, bh, bl, acc);
#pragma unroll
            for (int nt = 0; nt < 4; ++nt) {
                float m = fmaxf(fmaxf(acc[nt].x, acc[nt].y), fmaxf(acc[nt].z, acc[nt].w));
                zacc[nt] = fmaxf(zacc[nt], fmaxf(m + b2v[nt], 0.0f));
            }
        }
        if (t2 + 1 < TPW) {
            if (t2 + 2 < TPW)
                frag_fetch<PT, KP, KREAL>(U, V, idxa, idxa, pbase, t2 + 2, lane, r0);
            v8s ah[2], al[2];
            frag_pack(r1, ah, al);
            f32x4 acc[4];
            edge_mfma(ah, al, bh, bl, acc);
#pragma unroll
            for (int nt = 0; nt < 4; ++nt) {
                float m = fmaxf(fmaxf(acc[nt].x, acc[nt].y), fmaxf(acc[nt].z, acc[nt].w));
                zacc[nt] = fmaxf(zacc[nt], fmaxf(m + b2v[nt], 0.0f));
            }
        }
    }

#pragma unroll
    for (int nt = 0; nt < 4; ++nt) {
        float zm = fmaxf(zacc[nt], __shfl_xor(zacc[nt], 16));
        zm = fmaxf(zm, __shfl_xor(zm, 32));
        if (quad == 0) {
            atomicMax((unsigned int*)(outp + (size_t)g * 64 + nt * 16 + col),
                      __float_as_uint(zm));
        }
    }
}

// ---------------------------------------------------------------------------
// Kernel 4: final 64->6 regression from pooled. 6 blocks x 64 threads.
// ---------------------------------------------------------------------------
__global__ __launch_bounds__(64) void reg_kernel(
    const float* __restrict__ pooled, const float* __restrict__ regW,
    const float* __restrict__ regb, float* __restrict__ out)
{
    const int t = blockIdx.x * 64 + threadIdx.x;
    const int b = t / 6;
    const int o = t - b * 6;
    if (t < NB * 6) {
        float z = regb[o];
        const float* pb = pooled + (size_t)b * 64;
        for (int c = 0; c < 64; ++c) z = fmaf(pb[c], regW[c * 6 + o], z);
        out[b * 6 + o] = z;
    }
}

// ---------------------------------------------------------------------------
extern "C" void kernel_launch(void* const* d_in, const int* in_sizes, int n_in,
                              void* d_out, int out_size, void* d_ws, size_t ws_size,
                              hipStream_t stream)
{
    (void)in_sizes; (void)n_in; (void)out_size; (void)ws_size;
    const float* pos   = (const float*)d_in[1];
    const float* c1W1  = (const float*)d_in[3];
    const float* c1b1  = (const float*)d_in[4];
    const float* c1W2  = (const float*)d_in[5];
    const float* c1b2  = (const float*)d_in[6];
    const float* c2W1  = (const float*)d_in[7];
    const float* c2b1  = (const float*)d_in[8];
    const float* c2W2  = (const float*)d_in[9];
    const float* c2b2  = (const float*)d_in[10];
    const float* c3W1  = (const float*)d_in[11];
    const float* c3b1  = (const float*)d_in[12];
    const float* c3W2  = (const float*)d_in[13];
    const float* c3b2  = (const float*)d_in[14];
    const float* regW  = (const float*)d_in[15];
    const float* regb  = (const float*)d_in[16];
    float* out = (float*)d_out;

    // workspace: idx | A | C | D | E | pooled | packed-weights (112 KB)
    char* ws = (char*)d_ws;
    int*   idx = (int*)ws;                                    // 1.5 MB
    float* A = (float*)(ws + 1572864);
    float* C = (float*)(ws + 1572864 + 1 * 16777216);
    float* D = (float*)(ws + 1572864 + 2 * 16777216);
    float* E = (float*)(ws + 1572864 + 3 * 16777216);
    float* pooled = (float*)(ws + 1572864 + 4 * 16777216);    // 16 KB
    char*  pw = ws + 1572864 + 4 * 16777216 + 16384;
    const v8s* c1W2ph = (const v8s*)(pw);
    const v8s* c1W2pl = (const v8s*)(pw + 8192);
    const v8s* c2W2ph = (const v8s*)(pw + 16384);
    const v8s* c2W2pl = (const v8s*)(pw + 24576);
    const v8s* c3W2ph = (const v8s*)(pw + 32768);
    const v8s* c3W2pl = (const v8s*)(pw + 40960);
    const v8s* c2W1ph = (const v8s*)(pw + 49152);
    const v8s* c2W1pl = (const v8s*)(pw + 65536);
    const v8s* c3W1ph = (const v8s*)(pw + 81920);
    const v8s* c3W1pl = (const v8s*)(pw + 98304);

    // pack all weight fragments once (tiny)
    packw_kernel<<<14, 256, 0, stream>>>(c1W2, c2W2, c3W2, c2W1, c3W1, pw);

    // kNN + layer-1 prep (U1 -> D, Vpos -> C) in one launch
    knn6_prep_kernel<<<NB * 16, 256, 0, stream>>>(pos, c1W1, c1b1, idx, D, C);

    // fused layer1-edge + layer2-uv: reads (D=U1, C=Vpos) -> U2->A, V2->E
    fused_edge_uv_kernel<2, 8, 6><<<1024, 256, 0, stream>>>(
        D, C, idx, c1W2ph, c1W2pl, c1b2, c2W1ph, c2W1pl, c2W1, c2b1, pos,
        A, E, nullptr);

    // fused layer2-edge + layer3-uv: reads (A=U2, E=V2) -> U3->D, V3->C
    // (block 0 zeroes pooled)
    fused_edge_uv_kernel<4, 4, 4><<<1024, 256, 0, stream>>>(
        A, E, idx, c2W2ph, c2W2pl, c2b2, c3W1ph, c3W1pl, c3W1, c3b1, pos,
        D, C, pooled);

    // layer3 edge -> atomic max into pooled
    edge3_mfma_kernel<4, 4, 3, 2><<<2048, 256, 0, stream>>>(
        D, C, idx, c3W2ph, c3W2pl, c3b2, pooled);

    // final regression
    reg_kernel<<<6, 64, 0, stream>>>(pooled, regW, regb, out);
}